// Round 8
// baseline (256.146 us; speedup 1.0000x reference)
//
#include <hip/hip_runtime.h>
#include <hip/hip_bf16.h>
#include <math.h>

#define BB 8
#define NN 128
#define HN 256
#define HE 128
#define NH 8
#define DH 32
#define PP 8128
#define BP (BB*PP)   // 65024

typedef __hip_bfloat16 bf16;
typedef __attribute__((ext_vector_type(8))) short bf16x8;

__device__ __forceinline__ float bf2f(bf16 x){ return __bfloat162float(x); }
__device__ __forceinline__ float bfraw2f(short u){
  return __uint_as_float(((unsigned)(unsigned short)u) << 16);
}

__device__ __forceinline__ float wave_sum(float v){
  #pragma unroll
  for (int off=32; off>=1; off>>=1) v += __shfl_xor(v, off, 64);
  return v;
}
__device__ __forceinline__ float g16_sum(float v){
  #pragma unroll
  for (int off=8; off>=1; off>>=1) v += __shfl_xor(v, off, 16);
  return v;
}

// triu pair index for N=128, i<j: p = i*(255-i)/2 + (j-i-1)
__device__ __forceinline__ int pair_idx(int a, int c){
  int i = a < c ? a : c;
  int j = a < c ? c : a;
  return ((i*(255 - i))>>1) + (j - i - 1);
}

// ---- canonical fp32 workspace layout (float offsets). edge_feat NOT converted. ----
#define C_NODE 0LL
#define C_MASK 262144LL
#define C_WQKV 327168LL
#define C_BQKV 523776LL
#define C_WEV  524544LL
#define C_BEV  557312LL
#define C_WEA  557568LL
#define C_BEA  558592LL
#define C_WO   558600LL
#define C_BO   689672LL
#define C_WSK  689928LL
#define C_BSK  821000LL
#define C_GN   821512LL
#define C_BN   821768LL
#define C_GE   822024LL
#define C_BE   822152LL
#define IOFF   822400LL
#define TOT8   102785
#define CONVBLKS 402          // ceil(TOT8/256)
// intermediates (float offsets from IOFF)
#define I_NIN  0LL
#define I_Q    262144LL
#define I_K    524288LL
#define I_V    786432LL
#define I_EA2  1572864LL   // [B][PP][8] f32 = 520192
#define I_XG   2093056LL   // [BP][128] bf16 = 4161536 float-slots
#define I_WT   14577664LL  // [256][128] bf16 = 16384 float-slots
#define I_WOT  14594048LL  // WoT [256][512] bf16 = 65536 float-slots
#define I_WSKT 14659584LL  // WskT [512][256] bf16 = 65536 float-slots
#define I_FLG  14725120LL

// ---------------- Converter + Wev^T + WoT/WskT (transposed bf16) + dtype detect --
struct SrcPtrs { const void* p[16]; };

__global__ __launch_bounds__(256) void k_convert(SrcPtrs sp, float* __restrict__ dst,
                                                 int* __restrict__ flags,
                                                 const unsigned short* __restrict__ nodeRaw,
                                                 const void* __restrict__ rawWev,
                                                 bf16* __restrict__ Wt,
                                                 const void* __restrict__ rawWo,
                                                 const void* __restrict__ rawWsk,
                                                 bf16* __restrict__ WoT,
                                                 bf16* __restrict__ WskT)
{
  __shared__ int sbad;
  if (threadIdx.x == 0) sbad = 0;
  __syncthreads();
  {
    int bad = 0;
    for (int i = threadIdx.x; i < 1024; i += 256){
      unsigned e = (nodeRaw[i] >> 7) & 0xFFu;
      if (e >= 194u) bad = 1;
    }
    if (bad) sbad = 1;
  }
  __syncthreads();
  const int f32 = sbad;        // 1 = inputs fp32, 0 = bf16
  if (blockIdx.x == 0 && threadIdx.x == 0) flags[0] = f32;

  if (blockIdx.x >= CONVBLKS + 128){
    // WoT[n][k] = Wo[k][n] (256x512), WskT[c][k] = Wsk[k][c] (512x256), bf16.
    // Output-major: one 16B write per thread, 8 strided reads (L2-hot weights).
    int o = (blockIdx.x - (CONVBLKS + 128))*256 + threadIdx.x;   // < 32768 octets
    union { float4 f; bf16 h[8]; } cv;
    if (o < 16384){
      int outb = o*8;                 // flat into WoT[256][512]
      int n = outb >> 9, k0 = outb & 511;
      if (f32){
        const float* src = (const float*)rawWo;
        #pragma unroll
        for (int i=0;i<8;i++) cv.h[i] = __float2bfloat16(src[(long)(k0+i)*HN + n]);
      } else {
        const bf16* src = (const bf16*)rawWo;
        #pragma unroll
        for (int i=0;i<8;i++) cv.h[i] = src[(long)(k0+i)*HN + n];   // bit-exact
      }
      *reinterpret_cast<float4*>(WoT + outb) = cv.f;
    } else {
      int lo = o - 16384;
      int outb = lo*8;                // flat into WskT[512][256]
      int c = outb >> 8, k0 = outb & 255;
      if (f32){
        const float* src = (const float*)rawWsk;
        #pragma unroll
        for (int i=0;i<8;i++) cv.h[i] = __float2bfloat16(src[(long)(k0+i)*512 + c]);
      } else {
        const bf16* src = (const bf16*)rawWsk;
        #pragma unroll
        for (int i=0;i<8;i++) cv.h[i] = src[(long)(k0+i)*512 + c];  // bit-exact
      }
      *reinterpret_cast<float4*>(WskT + outb) = cv.f;
    }
    return;
  }

  if (blockIdx.x >= CONVBLKS){
    // Wev transpose from RAW input: idx over [128][256] -> Wt [256][128] bf16
    int idx = (blockIdx.x - CONVBLKS)*256 + threadIdx.x;   // < 32768
    float v = f32 ? ((const float*)rawWev)[idx]
                  : bfraw2f(((const short*)rawWev)[idx]);
    Wt[(idx & 255)*128 + (idx >> 8)] = __float2bfloat16(v);
    return;
  }

  int o = blockIdx.x*256 + threadIdx.x;
  if (o >= TOT8) return;
  const int cum[17] = {0,32768,40896,65472,65568,69664,69696,69824,69825,
                       86209,86241,102625,102689,102721,102753,102769,102785};
  int s = 0;
  #pragma unroll
  for (int i = 1; i <= 15; i++) if (o >= cum[i]) s = i;
  const int li = o - cum[s];
  float4 r0, r1;
  if (f32){
    const float4* src = (const float4*)sp.p[s];
    r0 = src[2*li]; r1 = src[2*li+1];
  } else {
    union { float4 f; unsigned short u[8]; } cv;
    cv.f = ((const float4*)sp.p[s])[li];
    r0.x = __uint_as_float((unsigned)cv.u[0] << 16);
    r0.y = __uint_as_float((unsigned)cv.u[1] << 16);
    r0.z = __uint_as_float((unsigned)cv.u[2] << 16);
    r0.w = __uint_as_float((unsigned)cv.u[3] << 16);
    r1.x = __uint_as_float((unsigned)cv.u[4] << 16);
    r1.y = __uint_as_float((unsigned)cv.u[5] << 16);
    r1.z = __uint_as_float((unsigned)cv.u[6] << 16);
    r1.w = __uint_as_float((unsigned)cv.u[7] << 16);
  }
  float4* d = (float4*)(dst + (long long)cum[s]*8);
  d[2*li]   = r0;
  d[2*li+1] = r1;
}

// ---------------- Kernel 1: node LN + QKV GEMM, column-split x3 ----------------
// grid 768 = 256 rowgroups(4 rows) x 3 outputs {q,k,v}; block 256
// v is stored row-major [b][n][256] (col = h*32+d) for the fused attention kernel.
__global__ __launch_bounds__(256) void k1_node_ln_qkv(
    const float* __restrict__ cnode, const float* __restrict__ cWqkv,
    const float* __restrict__ cbqkv, const float* __restrict__ cgn, const float* __restrict__ cbn,
    float* __restrict__ nin_ws, float* __restrict__ q_ws, float* __restrict__ k_ws,
    float* __restrict__ v_ws)
{
  __shared__ float xln[4][HN];
  const int t = threadIdx.x, wv = t>>6, lane = t&63;
  const int cb = blockIdx.x % 3;           // 0=q, 1=k, 2=v
  const int g0 = (blockIdx.x / 3) * 4;
  {
    int g = g0 + wv;
    float x[4];
    #pragma unroll
    for (int i=0;i<4;i++) x[i] = cnode[g*HN + lane + 64*i];
    float s = x[0]+x[1]+x[2]+x[3];
    s = wave_sum(s);
    float m = s * (1.0f/HN);
    float q = 0.f;
    #pragma unroll
    for (int i=0;i<4;i++){ float d = x[i]-m; q += d*d; }
    q = wave_sum(q);
    float rstd = rsqrtf(fmaxf(q*(1.0f/HN), 0.f) + 1e-5f);
    #pragma unroll
    for (int i=0;i<4;i++){
      int c = lane + 64*i;
      float y = (x[i]-m)*rstd*cgn[c] + cbn[c];
      xln[wv][c] = y;
      if (cb == 0) nin_ws[g*HN + c] = y;
    }
  }
  __syncthreads();
  const int col = cb*256 + t;
  float acc[4];
  {
    float bb = cbqkv[col];
    #pragma unroll
    for (int r=0;r<4;r++) acc[r] = bb;
  }
  for (int k=0;k<HN;k+=4){
    float4 xv[4];
    #pragma unroll
    for (int r=0;r<4;r++) xv[r] = *reinterpret_cast<const float4*>(&xln[r][k]);
    #pragma unroll
    for (int kk=0;kk<4;kk++){
      float w = cWqkv[(k+kk)*768 + col];
      #pragma unroll
      for (int r=0;r<4;r++) acc[r] = fmaf((&xv[r].x)[kk], w, acc[r]);
    }
  }
  if (cb == 2){
    // v: row-major [b][n][256], col = t = h*32+d
    #pragma unroll
    for (int r=0;r<4;r++) v_ws[(long)(g0+r)*HN + t] = acc[r];
  } else {
    float* dstp = (cb == 0) ? q_ws : k_ws;
    const int h = t>>5, d = t&31;
    #pragma unroll
    for (int r=0;r<4;r++){
      int g = g0 + r;
      int b = g>>7, n = g&127;
      dstp[((b*NH + h)*NN + n)*DH + d] = acc[r];
    }
  }
}

// ---------------- k2a: edge LN -> xg (bf16), Wea GEMM + mask fold -> ea2 ----------
// grid 4064 (16 rows/block), block 256
// ea2 layout is [b][p][8] so the attention kernel gathers 32 contiguous bytes/pair.
__global__ __launch_bounds__(256) void k2a_edge_ln(
    const void* __restrict__ edge_raw, const float* __restrict__ cWea,
    const float* __restrict__ cbea, const float* __restrict__ cge,
    const float* __restrict__ cbe, const float* __restrict__ cmask,
    bf16* __restrict__ xg, float* __restrict__ ea2, const int* __restrict__ flags)
{
  __shared__ float xlnS[16][136];
  __shared__ float part[128];
  const int t = threadIdx.x;
  const int R0 = blockIdx.x*16;
  const int b = R0 / PP;
  const int p0 = R0 - b*PP;
  const int f32 = flags[0];
  {
    int r = t>>4, sub = t&15;
    long base = (long)(R0 + r)*HE + sub*8;
    float x[8];
    if (f32){
      const float* cef = (const float*)edge_raw + base;
      float4 a0 = *reinterpret_cast<const float4*>(cef);
      float4 a1 = *reinterpret_cast<const float4*>(cef + 4);
      x[0]=a0.x; x[1]=a0.y; x[2]=a0.z; x[3]=a0.w;
      x[4]=a1.x; x[5]=a1.y; x[6]=a1.z; x[7]=a1.w;
    } else {
      union { float4 f; short u[8]; } cv;
      cv.f = *reinterpret_cast<const float4*>((const bf16*)edge_raw + base);
      #pragma unroll
      for (int i=0;i<8;i++) x[i] = bfraw2f(cv.u[i]);
    }
    float s = 0.f;
    #pragma unroll
    for (int i=0;i<8;i++) s += x[i];
    s = g16_sum(s);
    float m = s*(1.0f/HE);
    float q = 0.f;
    #pragma unroll
    for (int i=0;i<8;i++){ float dd = x[i]-m; q += dd*dd; }
    q = g16_sum(q);
    float rstd = rsqrtf(fmaxf(q*(1.0f/HE), 0.f) + 1e-5f);
    float y[8];
    #pragma unroll
    for (int i=0;i<8;i++){
      int c = sub*8 + i;
      y[i] = (x[i]-m)*rstd*cge[c] + cbe[c];
    }
    float4 y0; y0.x=y[0]; y0.y=y[1]; y0.z=y[2]; y0.w=y[3];
    float4 y1; y1.x=y[4]; y1.y=y[5]; y1.z=y[6]; y1.w=y[7];
    *reinterpret_cast<float4*>(&xlnS[r][sub*8])     = y0;
    *reinterpret_cast<float4*>(&xlnS[r][sub*8 + 4]) = y1;
  }
  __syncthreads();
  // write xg: thread -> row = t>>4, 8 consecutive cols
  {
    int r = t>>4, c0 = (t&15)*8;
    union { float4 f; bf16 h[8]; } o;
    #pragma unroll
    for (int i=0;i<8;i++) o.h[i] = __float2bfloat16(xlnS[r][c0+i]);
    *reinterpret_cast<float4*>(xg + (long)(R0 + r)*HE + c0) = o.f;
  }
  // e_adj (+mask fold): all 256 threads; (r,c) with k-range split by half
  {
    const int c = t & 7, r = (t>>3) & 15, half = t>>7;
    const int pid = r*8 + c;
    float s = half ? 0.0f : cbea[c];
    const int k0 = half*64;
    #pragma unroll 8
    for (int k=k0; k<k0+64; k++) s = fmaf(xlnS[r][k], cWea[k*NH + c], s);
    if (half){ part[pid] = s; }
    __syncthreads();
    if (!half){
      s += part[pid];
      int p = p0 + r;
      float mk = cmask[b*PP + p];
      ea2[((long)b*PP + p)*8 + c] = (mk != 0.0f) ? s : -9e15f;
    }
  }
}

// ------- k345: fused attention + Wo/GELU + Wsk/gate/residual, per (b,n) row ------
// k3's block (b,n) produces the ENTIRE attn row (8 heads x 32 = 256 cols = t),
// and k4/k5 are row-local -> run them as tail phases on LDS, no extra launches.
// grid B*N = 1024 (XCD-swizzled); block 256 (32 lanes/head); LDS 36.9KB -> 4 blk/CU
__global__ __launch_bounds__(256, 4) void k345(
    const float* __restrict__ q_ws,   // [b][h][n][32]
    const float* __restrict__ k_ws,   // [b][h][n][32]
    const float* __restrict__ v_ws,   // [b][n][256]
    const bf16* __restrict__ xg,      // [b*PP][128]
    const float* __restrict__ ea2,    // [b][PP][8]
    const bf16* __restrict__ Wt,      // [256][128]  (Wev^T)
    const float* __restrict__ cbev,   // [256]
    const float* __restrict__ nin_ws, // [b*n][256]
    const bf16* __restrict__ WoT,     // [256][512]  (Wo^T)
    const float* __restrict__ cbo,    // [256]
    const bf16* __restrict__ WskT,    // [512][256]  (Wsk^T)
    const float* __restrict__ cbsk,   // [512]
    const float* __restrict__ cnode,  // canonical fp32 node
    void* __restrict__ out, const int* __restrict__ flags)
{
  __shared__ __align__(16) bf16  xgS[128][128];   // 32 KB gathered neighbor rows
  __shared__ __align__(16) float sS[8][128];      // 4 KB per-head S vectors
  float* xc    = (float*)xgS;        // [512] aliases xgS after phase C
  float* combS = xc + 512;           // [256]
  const int t = threadIdx.x;
  const int bid = blockIdx.x;
  const int swz = (bid & 7)*128 + (bid >> 3);   // XCD j owns contiguous swz range = one b
  const int n = swz & 127, b = swz >> 7;
  const int g = b*NN + n;
  const int h = t >> 5, ln = t & 31;

  // ---- Issue phase: all global loads go out before any compute/barrier ----
  float4 qv[8];
  const float* qb = q_ws + (((long)b*NH + h)*NN + n)*DH;
  #pragma unroll
  for (int d4=0; d4<8; d4++) qv[d4] = *reinterpret_cast<const float4*>(qb + d4*4);
  float eav[4];
  const float* eab = ea2 + (long)b*PP*8;
  #pragma unroll
  for (int j=0;j<4;j++){
    int m = ln + 32*j;
    int ms = (m == n) ? (m ^ 1) : m;
    eav[j] = eab[(long)pair_idx(n, ms)*8 + h];
  }
  const bf16* xgb = xg + (long)b*PP*HE;
  const int rowb = t >> 4, seg = t & 15;
  float4 xr[8];
  #pragma unroll
  for (int it=0; it<8; ++it){
    int row = it*16 + rowb;
    int ms = (row == n) ? (row ^ 1) : row;
    int pr = pair_idx(n, ms);
    xr[it] = *reinterpret_cast<const float4*>(xgb + (long)pr*HE + seg*8);
  }

  // ---- Phase B: fp32 QK dots + per-head softmax, no LDS, no barrier ----
  const float scale = 0.17677669529663687f;  // 32^-0.5
  const float* kb = k_ws + ((long)b*NH + h)*NN*DH;
  float l[4];
  float mx = -INFINITY;
  int valid = 0;
  #pragma unroll
  for (int j=0;j<4;j++){
    int m = ln + 32*j;
    const float* kr = kb + m*DH;
    float dot = 0.f;
    #pragma unroll
    for (int d4=0; d4<8; d4++){
      float4 kv = *reinterpret_cast<const float4*>(kr + d4*4);
      dot = fmaf(qv[d4].x, kv.x, dot);
      dot = fmaf(qv[d4].y, kv.y, dot);
      dot = fmaf(qv[d4].z, kv.z, dot);
      dot = fmaf(qv[d4].w, kv.w, dot);
    }
    bool self = (m == n);
    l[j] = self ? -INFINITY : fmaf(dot, scale, eav[j]);
    if (!self && eav[j] > -8.9e15f) valid = 1;
    mx = fmaxf(mx, l[j]);
  }
  #pragma unroll
  for (int off=16; off>=1; off>>=1) mx = fmaxf(mx, __shfl_xor(mx, off, 32));
  float e[4], s = 0.f;
  #pragma unroll
  for (int j=0;j<4;j++){ e[j] = __expf(l[j]-mx); s += e[j]; }
  float av = valid ? 1.f : 0.f;
  #pragma unroll
  for (int off=16; off>=1; off>>=1){
    s  += __shfl_xor(s,  off, 32);
    av += __shfl_xor(av, off, 32);
  }
  float inv = (av > 0.f) ? (1.0f/s) : 0.f;
  float pj0 = e[0]*inv, pj1 = e[1]*inv, pj2 = e[2]*inv, pj3 = e[3]*inv;

  // ---- Stage gathered xg rows to LDS (loads landed during Phase B) ----
  #pragma unroll
  for (int it=0; it<8; ++it){
    int row = it*16 + rowb;
    *reinterpret_cast<float4*>(&xgS[row][seg*8]) = xr[it];
  }
  __syncthreads();

  // ---- Phase C: branch-free p-weighted accumulate (p via shuffle broadcast) ----
  const float* vb = v_ws + (long)b*NN*HN + h*DH + ln;
  float S0=0.f,S1=0.f,S2=0.f,S3=0.f,T=0.f;
  #pragma unroll
  for (int j=0;j<4;j++){
    float pcur = (j==0) ? pj0 : (j==1) ? pj1 : (j==2) ? pj2 : pj3;
    #pragma unroll 2
    for (int mm=0; mm<32; mm+=4){
      #pragma unroll
      for (int i=0;i<4;i++){
        int m = j*32 + mm + i;
        float pm = __shfl(pcur, mm + i, 32);
        short4 xv = *reinterpret_cast<const short4*>(&xgS[m][ln*4]);
        S0 = fmaf(pm, bfraw2f(xv.x), S0);
        S1 = fmaf(pm, bfraw2f(xv.y), S1);
        S2 = fmaf(pm, bfraw2f(xv.z), S2);
        S3 = fmaf(pm, bfraw2f(xv.w), S3);
        T  = fmaf(pm, vb[m*HN], T);
      }
    }
  }
  {
    float4 sv; sv.x=S0; sv.y=S1; sv.z=S2; sv.w=S3;
    *reinterpret_cast<float4*>(&sS[h][ln*4]) = sv;
  }
  __syncthreads();   // after this barrier xgS is dead -> xc/combS may be written

  // ---- Phase D: per-head 128x32 matvec with Wt, + bev + v-part = attn col t ----
  float nin_v = nin_ws[(long)g*HN + t];   // issue early; lands under matvec
  float acc = T + ((av > 0.f) ? cbev[t] : 0.f);
  const bf16* wr = Wt + t*HE;
  #pragma unroll 4
  for (int k0=0;k0<128;k0+=8){
    float4 sa = *reinterpret_cast<const float4*>(&sS[h][k0]);
    float4 sb = *reinterpret_cast<const float4*>(&sS[h][k0+4]);
    bf16x8 wv = *reinterpret_cast<const bf16x8*>(wr + k0);
    acc = fmaf(sa.x, bfraw2f(wv[0]), acc);
    acc = fmaf(sa.y, bfraw2f(wv[1]), acc);
    acc = fmaf(sa.z, bfraw2f(wv[2]), acc);
    acc = fmaf(sa.w, bfraw2f(wv[3]), acc);
    acc = fmaf(sb.x, bfraw2f(wv[4]), acc);
    acc = fmaf(sb.y, bfraw2f(wv[5]), acc);
    acc = fmaf(sb.z, bfraw2f(wv[6]), acc);
    acc = fmaf(sb.w, bfraw2f(wv[7]), acc);
  }
  xc[t]       = nin_v;
  xc[256 + t] = acc;
  __syncthreads();

  // ---- Phase E (k4): comb col t = GELU(bo + concat(nin,attn) . WoT[t]) ----
  float co = cbo[t];
  const bf16* worow = WoT + t*512;
  #pragma unroll 8
  for (int k0=0;k0<512;k0+=8){
    bf16x8 w8 = *reinterpret_cast<const bf16x8*>(worow + k0);
    float4 xa = *reinterpret_cast<const float4*>(&xc[k0]);
    float4 xb = *reinterpret_cast<const float4*>(&xc[k0+4]);
    co = fmaf(xa.x, bfraw2f(w8[0]), co);
    co = fmaf(xa.y, bfraw2f(w8[1]), co);
    co = fmaf(xa.z, bfraw2f(w8[2]), co);
    co = fmaf(xa.w, bfraw2f(w8[3]), co);
    co = fmaf(xb.x, bfraw2f(w8[4]), co);
    co = fmaf(xb.y, bfraw2f(w8[5]), co);
    co = fmaf(xb.z, bfraw2f(w8[6]), co);
    co = fmaf(xb.w, bfraw2f(w8[7]), co);
  }
  co = 0.5f*co*(1.0f + erff(co*0.7071067811865475f));
  combS[t] = co;
  __syncthreads();

  // ---- Phase F (k5): val/gate cols t / t+256, sigmoid gate + residual ----
  float av5 = cbsk[t], ag5 = cbsk[t+256];
  const bf16* wvrow = WskT + t*256;
  const bf16* wgrow = WskT + (t+256)*256;
  #pragma unroll 4
  for (int k0=0;k0<256;k0+=8){
    bf16x8 wv8 = *reinterpret_cast<const bf16x8*>(wvrow + k0);
    bf16x8 wg8 = *reinterpret_cast<const bf16x8*>(wgrow + k0);
    float4 ca = *reinterpret_cast<const float4*>(&combS[k0]);
    float4 cb2 = *reinterpret_cast<const float4*>(&combS[k0+4]);
    av5 = fmaf(ca.x,  bfraw2f(wv8[0]), av5);
    av5 = fmaf(ca.y,  bfraw2f(wv8[1]), av5);
    av5 = fmaf(ca.z,  bfraw2f(wv8[2]), av5);
    av5 = fmaf(ca.w,  bfraw2f(wv8[3]), av5);
    av5 = fmaf(cb2.x, bfraw2f(wv8[4]), av5);
    av5 = fmaf(cb2.y, bfraw2f(wv8[5]), av5);
    av5 = fmaf(cb2.z, bfraw2f(wv8[6]), av5);
    av5 = fmaf(cb2.w, bfraw2f(wv8[7]), av5);
    ag5 = fmaf(ca.x,  bfraw2f(wg8[0]), ag5);
    ag5 = fmaf(ca.y,  bfraw2f(wg8[1]), ag5);
    ag5 = fmaf(ca.z,  bfraw2f(wg8[2]), ag5);
    ag5 = fmaf(ca.w,  bfraw2f(wg8[3]), ag5);
    ag5 = fmaf(cb2.x, bfraw2f(wg8[4]), ag5);
    ag5 = fmaf(cb2.y, bfraw2f(wg8[5]), ag5);
    ag5 = fmaf(cb2.z, bfraw2f(wg8[6]), ag5);
    ag5 = fmaf(cb2.w, bfraw2f(wg8[7]), ag5);
  }
  float gg = 1.0f/(1.0f + __expf(-ag5));
  long idx = (long)g*HN + t;
  float nf = cnode[idx];
  float res = nf*(1.0f - gg) + av5*gg;
  if (flags[0]) ((float*)out)[idx] = res;
  else ((bf16*)out)[idx] = __float2bfloat16(res);
}

extern "C" void kernel_launch(void* const* d_in, const int* in_sizes, int n_inputs,
                              void* d_out, int out_size, void* d_ws, size_t ws_size,
                              hipStream_t stream)
{
  float* ws = (float*)d_ws;
  float* c_node = ws + C_NODE;
  float* c_mask = ws + C_MASK;
  float* c_Wqkv = ws + C_WQKV;
  float* c_bqkv = ws + C_BQKV;
  float* c_bev  = ws + C_BEV;
  float* c_Wea  = ws + C_WEA;
  float* c_bea  = ws + C_BEA;
  float* c_bo   = ws + C_BO;
  float* c_bsk  = ws + C_BSK;
  float* c_gn   = ws + C_GN;
  float* c_bn   = ws + C_BN;
  float* c_ge   = ws + C_GE;
  float* c_be   = ws + C_BE;
  float* base   = ws + IOFF;
  float* nin_ws  = base + I_NIN;
  float* q_ws    = base + I_Q;
  float* k_ws    = base + I_K;
  float* v_ws    = base + I_V;
  float* ea2_ws  = base + I_EA2;
  bf16*  xg_ws   = (bf16*)(base + I_XG);
  bf16*  wt_ws   = (bf16*)(base + I_WT);
  bf16*  wot_ws  = (bf16*)(base + I_WOT);
  bf16*  wskt_ws = (bf16*)(base + I_WSKT);
  int*   flags   = (int*)(base + I_FLG);

  SrcPtrs sp;
  sp.p[0]  = d_in[0];   // node_feat
  sp.p[1]  = d_in[4];   // mask_valid
  sp.p[2]  = d_in[5];   // Wqkv
  sp.p[3]  = d_in[6];   // bqkv
  sp.p[4]  = d_in[7];   // Wev
  sp.p[5]  = d_in[8];   // bev
  sp.p[6]  = d_in[9];   // Wea
  sp.p[7]  = d_in[10];  // bea
  sp.p[8]  = d_in[11];  // Wo
  sp.p[9]  = d_in[12];  // bo
  sp.p[10] = d_in[13];  // Wsk
  sp.p[11] = d_in[14];  // bsk
  sp.p[12] = d_in[15];  // gn
  sp.p[13] = d_in[16];  // bn
  sp.p[14] = d_in[17];  // ge
  sp.p[15] = d_in[18];  // be

  k_convert<<<CONVBLKS + 256, 256, 0, stream>>>(sp, ws, flags,
                                                (const unsigned short*)d_in[0],
                                                d_in[7], wt_ws,
                                                d_in[11], d_in[13],
                                                wot_ws, wskt_ws);
  k1_node_ln_qkv<<<768, 256, 0, stream>>>(c_node, c_Wqkv, c_bqkv, c_gn, c_bn,
                                          nin_ws, q_ws, k_ws, v_ws);
  k2a_edge_ln<<<BP/16, 256, 0, stream>>>(d_in[1], c_Wea, c_bea, c_ge, c_be, c_mask,
                                         xg_ws, ea2_ws, flags);
  k345<<<BB*NN, 256, 0, stream>>>(q_ws, k_ws, v_ws, xg_ws, ea2_ws, wt_ws, c_bev,
                                  nin_ws, wot_ws, c_bo, wskt_ws, c_bsk,
                                  c_node, d_out, flags);
}

// Round 9
// 207.439 us; speedup vs baseline: 1.2348x; 1.2348x over previous
//
#include <hip/hip_runtime.h>
#include <hip/hip_bf16.h>
#include <math.h>

#define BB 8
#define NN 128
#define HN 256
#define HE 128
#define NH 8
#define DH 32
#define PP 8128
#define BP (BB*PP)   // 65024

typedef __hip_bfloat16 bf16;
typedef __attribute__((ext_vector_type(8))) short bf16x8;

__device__ __forceinline__ float bf2f(bf16 x){ return __bfloat162float(x); }
__device__ __forceinline__ float bfraw2f(short u){
  return __uint_as_float(((unsigned)(unsigned short)u) << 16);
}

__device__ __forceinline__ float wave_sum(float v){
  #pragma unroll
  for (int off=32; off>=1; off>>=1) v += __shfl_xor(v, off, 64);
  return v;
}
__device__ __forceinline__ float g16_sum(float v){
  #pragma unroll
  for (int off=8; off>=1; off>>=1) v += __shfl_xor(v, off, 16);
  return v;
}

// triu pair index for N=128, i<j: p = i*(255-i)/2 + (j-i-1)
__device__ __forceinline__ int pair_idx(int a, int c){
  int i = a < c ? a : c;
  int j = a < c ? c : a;
  return ((i*(255 - i))>>1) + (j - i - 1);
}

// ---- canonical fp32 workspace layout (float offsets). edge_feat NOT converted. ----
#define C_NODE 0LL
#define C_MASK 262144LL
#define C_WQKV 327168LL
#define C_BQKV 523776LL
#define C_WEV  524544LL
#define C_BEV  557312LL
#define C_WEA  557568LL
#define C_BEA  558592LL
#define C_WO   558600LL
#define C_BO   689672LL
#define C_WSK  689928LL
#define C_BSK  821000LL
#define C_GN   821512LL
#define C_BN   821768LL
#define C_GE   822024LL
#define C_BE   822152LL
#define IOFF   822400LL
#define TOT8   102785
#define CONVBLKS 402          // ceil(TOT8/256)
// intermediates (float offsets from IOFF)
#define I_NIN  0LL
#define I_Q    262144LL
#define I_K    524288LL
#define I_V    786432LL
#define I_EA2  1572864LL   // [B][PP][8] f32 = 520192
#define I_XG   2093056LL   // [BP][128] bf16 = 4161536 float-slots
#define I_WT   14577664LL  // [256][128] bf16 = 16384 float-slots
#define I_WOB  14594048LL  // WoB [512][256] bf16 = 65536 float-slots
#define I_WSKB 14659584LL  // WskB [256][512] bf16 = 65536 float-slots
#define I_FLG  14725120LL

// ---------------- Converter + Wev^T + WoB/WskB bf16 (same layout) + dtype detect --
struct SrcPtrs { const void* p[16]; };

__global__ __launch_bounds__(256) void k_convert(SrcPtrs sp, float* __restrict__ dst,
                                                 int* __restrict__ flags,
                                                 const unsigned short* __restrict__ nodeRaw,
                                                 const void* __restrict__ rawWev,
                                                 bf16* __restrict__ Wt,
                                                 const void* __restrict__ rawWo,
                                                 const void* __restrict__ rawWsk,
                                                 bf16* __restrict__ WoB,
                                                 bf16* __restrict__ WskB)
{
  __shared__ int sbad;
  if (threadIdx.x == 0) sbad = 0;
  __syncthreads();
  {
    int bad = 0;
    for (int i = threadIdx.x; i < 1024; i += 256){
      unsigned e = (nodeRaw[i] >> 7) & 0xFFu;
      if (e >= 194u) bad = 1;
    }
    if (bad) sbad = 1;
  }
  __syncthreads();
  const int f32 = sbad;        // 1 = inputs fp32, 0 = bf16
  if (blockIdx.x == 0 && threadIdx.x == 0) flags[0] = f32;

  if (blockIdx.x >= CONVBLKS + 128){
    // Wo / Wsk -> bf16, same [k][n] layout. 32768 octets total.
    int o = (blockIdx.x - (CONVBLKS + 128))*256 + threadIdx.x;   // < 32768
    const void* src = (o < 16384) ? rawWo : rawWsk;
    bf16* dw = (o < 16384) ? WoB : WskB;
    int lo = (o < 16384) ? o : o - 16384;
    if (f32){
      const float4* s4 = (const float4*)src;
      float4 a0 = s4[2*lo], a1 = s4[2*lo+1];
      union { float4 f; bf16 h[8]; } cv;
      cv.h[0]=__float2bfloat16(a0.x); cv.h[1]=__float2bfloat16(a0.y);
      cv.h[2]=__float2bfloat16(a0.z); cv.h[3]=__float2bfloat16(a0.w);
      cv.h[4]=__float2bfloat16(a1.x); cv.h[5]=__float2bfloat16(a1.y);
      cv.h[6]=__float2bfloat16(a1.z); cv.h[7]=__float2bfloat16(a1.w);
      *reinterpret_cast<float4*>(dw + lo*8) = cv.f;
    } else {
      *reinterpret_cast<float4*>(dw + lo*8) = ((const float4*)src)[lo];  // bit-exact copy
    }
    return;
  }

  if (blockIdx.x >= CONVBLKS){
    // Wev transpose from RAW input: idx over [128][256] -> Wt [256][128] bf16
    int idx = (blockIdx.x - CONVBLKS)*256 + threadIdx.x;   // < 32768
    float v = f32 ? ((const float*)rawWev)[idx]
                  : bfraw2f(((const short*)rawWev)[idx]);
    Wt[(idx & 255)*128 + (idx >> 8)] = __float2bfloat16(v);
    return;
  }

  int o = blockIdx.x*256 + threadIdx.x;
  if (o >= TOT8) return;
  const int cum[17] = {0,32768,40896,65472,65568,69664,69696,69824,69825,
                       86209,86241,102625,102689,102721,102753,102769,102785};
  int s = 0;
  #pragma unroll
  for (int i = 1; i <= 15; i++) if (o >= cum[i]) s = i;
  const int li = o - cum[s];
  float4 r0, r1;
  if (f32){
    const float4* src = (const float4*)sp.p[s];
    r0 = src[2*li]; r1 = src[2*li+1];
  } else {
    union { float4 f; unsigned short u[8]; } cv;
    cv.f = ((const float4*)sp.p[s])[li];
    r0.x = __uint_as_float((unsigned)cv.u[0] << 16);
    r0.y = __uint_as_float((unsigned)cv.u[1] << 16);
    r0.z = __uint_as_float((unsigned)cv.u[2] << 16);
    r0.w = __uint_as_float((unsigned)cv.u[3] << 16);
    r1.x = __uint_as_float((unsigned)cv.u[4] << 16);
    r1.y = __uint_as_float((unsigned)cv.u[5] << 16);
    r1.z = __uint_as_float((unsigned)cv.u[6] << 16);
    r1.w = __uint_as_float((unsigned)cv.u[7] << 16);
  }
  float4* d = (float4*)(dst + (long long)cum[s]*8);
  d[2*li]   = r0;
  d[2*li+1] = r1;
}

// ---------------- Kernel 1: node LN + QKV GEMM, column-split x3 ----------------
// grid 768 = 256 rowgroups(4 rows) x 3 outputs {q,k,v}; block 256
// v is stored row-major [b][n][256] (col = h*32+d) for the fused attention kernel.
__global__ __launch_bounds__(256) void k1_node_ln_qkv(
    const float* __restrict__ cnode, const float* __restrict__ cWqkv,
    const float* __restrict__ cbqkv, const float* __restrict__ cgn, const float* __restrict__ cbn,
    float* __restrict__ nin_ws, float* __restrict__ q_ws, float* __restrict__ k_ws,
    float* __restrict__ v_ws)
{
  __shared__ float xln[4][HN];
  const int t = threadIdx.x, wv = t>>6, lane = t&63;
  const int cb = blockIdx.x % 3;           // 0=q, 1=k, 2=v
  const int g0 = (blockIdx.x / 3) * 4;
  {
    int g = g0 + wv;
    float x[4];
    #pragma unroll
    for (int i=0;i<4;i++) x[i] = cnode[g*HN + lane + 64*i];
    float s = x[0]+x[1]+x[2]+x[3];
    s = wave_sum(s);
    float m = s * (1.0f/HN);
    float q = 0.f;
    #pragma unroll
    for (int i=0;i<4;i++){ float d = x[i]-m; q += d*d; }
    q = wave_sum(q);
    float rstd = rsqrtf(fmaxf(q*(1.0f/HN), 0.f) + 1e-5f);
    #pragma unroll
    for (int i=0;i<4;i++){
      int c = lane + 64*i;
      float y = (x[i]-m)*rstd*cgn[c] + cbn[c];
      xln[wv][c] = y;
      if (cb == 0) nin_ws[g*HN + c] = y;
    }
  }
  __syncthreads();
  const int col = cb*256 + t;
  float acc[4];
  {
    float bb = cbqkv[col];
    #pragma unroll
    for (int r=0;r<4;r++) acc[r] = bb;
  }
  for (int k=0;k<HN;k+=4){
    float4 xv[4];
    #pragma unroll
    for (int r=0;r<4;r++) xv[r] = *reinterpret_cast<const float4*>(&xln[r][k]);
    #pragma unroll
    for (int kk=0;kk<4;kk++){
      float w = cWqkv[(k+kk)*768 + col];
      #pragma unroll
      for (int r=0;r<4;r++) acc[r] = fmaf((&xv[r].x)[kk], w, acc[r]);
    }
  }
  if (cb == 2){
    // v: row-major [b][n][256], col = t = h*32+d
    #pragma unroll
    for (int r=0;r<4;r++) v_ws[(long)(g0+r)*HN + t] = acc[r];
  } else {
    float* dstp = (cb == 0) ? q_ws : k_ws;
    const int h = t>>5, d = t&31;
    #pragma unroll
    for (int r=0;r<4;r++){
      int g = g0 + r;
      int b = g>>7, n = g&127;
      dstp[((b*NH + h)*NN + n)*DH + d] = acc[r];
    }
  }
}

// ---------------- k2a: edge LN -> xg (bf16), Wea GEMM + mask fold -> ea2 ----------
// grid 4064 (16 rows/block), block 256
// ea2 layout is [b][p][8] so the attention kernel gathers 32 contiguous bytes/pair.
__global__ __launch_bounds__(256) void k2a_edge_ln(
    const void* __restrict__ edge_raw, const float* __restrict__ cWea,
    const float* __restrict__ cbea, const float* __restrict__ cge,
    const float* __restrict__ cbe, const float* __restrict__ cmask,
    bf16* __restrict__ xg, float* __restrict__ ea2, const int* __restrict__ flags)
{
  __shared__ float xlnS[16][136];
  __shared__ float part[128];
  const int t = threadIdx.x;
  const int R0 = blockIdx.x*16;
  const int b = R0 / PP;
  const int p0 = R0 - b*PP;
  const int f32 = flags[0];
  {
    int r = t>>4, sub = t&15;
    long base = (long)(R0 + r)*HE + sub*8;
    float x[8];
    if (f32){
      const float* cef = (const float*)edge_raw + base;
      float4 a0 = *reinterpret_cast<const float4*>(cef);
      float4 a1 = *reinterpret_cast<const float4*>(cef + 4);
      x[0]=a0.x; x[1]=a0.y; x[2]=a0.z; x[3]=a0.w;
      x[4]=a1.x; x[5]=a1.y; x[6]=a1.z; x[7]=a1.w;
    } else {
      union { float4 f; short u[8]; } cv;
      cv.f = *reinterpret_cast<const float4*>((const bf16*)edge_raw + base);
      #pragma unroll
      for (int i=0;i<8;i++) x[i] = bfraw2f(cv.u[i]);
    }
    float s = 0.f;
    #pragma unroll
    for (int i=0;i<8;i++) s += x[i];
    s = g16_sum(s);
    float m = s*(1.0f/HE);
    float q = 0.f;
    #pragma unroll
    for (int i=0;i<8;i++){ float dd = x[i]-m; q += dd*dd; }
    q = g16_sum(q);
    float rstd = rsqrtf(fmaxf(q*(1.0f/HE), 0.f) + 1e-5f);
    float y[8];
    #pragma unroll
    for (int i=0;i<8;i++){
      int c = sub*8 + i;
      y[i] = (x[i]-m)*rstd*cge[c] + cbe[c];
    }
    float4 y0; y0.x=y[0]; y0.y=y[1]; y0.z=y[2]; y0.w=y[3];
    float4 y1; y1.x=y[4]; y1.y=y[5]; y1.z=y[6]; y1.w=y[7];
    *reinterpret_cast<float4*>(&xlnS[r][sub*8])     = y0;
    *reinterpret_cast<float4*>(&xlnS[r][sub*8 + 4]) = y1;
  }
  __syncthreads();
  // write xg: thread -> row = t>>4, 8 consecutive cols
  {
    int r = t>>4, c0 = (t&15)*8;
    union { float4 f; bf16 h[8]; } o;
    #pragma unroll
    for (int i=0;i<8;i++) o.h[i] = __float2bfloat16(xlnS[r][c0+i]);
    *reinterpret_cast<float4*>(xg + (long)(R0 + r)*HE + c0) = o.f;
  }
  // e_adj (+mask fold): all 256 threads; (r,c) with k-range split by half
  {
    const int c = t & 7, r = (t>>3) & 15, half = t>>7;
    const int pid = r*8 + c;
    float s = half ? 0.0f : cbea[c];
    const int k0 = half*64;
    #pragma unroll 8
    for (int k=k0; k<k0+64; k++) s = fmaf(xlnS[r][k], cWea[k*NH + c], s);
    if (half){ part[pid] = s; }
    __syncthreads();
    if (!half){
      s += part[pid];
      int p = p0 + r;
      float mk = cmask[b*PP + p];
      ea2[((long)b*PP + p)*8 + c] = (mk != 0.0f) ? s : -9e15f;
    }
  }
}

// ------- k345: fused attention + Wo/GELU + Wsk/gate/residual, per (b,n) row ------
// Tail weight access is COALESCED (thread t = output col t, weights in original
// [k][n] layout): 256 consecutive bf16 per wave-instruction, rows broadcast
// across blocks/waves via L1/L2. Round-8's per-thread-row reads wasted ~4x L2
// sector BW (64 lines/instr) -> 89us tail; this is the fix.
// grid B*N = 1024 (XCD-swizzled); block 256 (32 lanes/head); LDS 36.9KB -> 4 blk/CU
__global__ __launch_bounds__(256, 4) void k345(
    const float* __restrict__ q_ws,   // [b][h][n][32]
    const float* __restrict__ k_ws,   // [b][h][n][32]
    const float* __restrict__ v_ws,   // [b][n][256]
    const bf16* __restrict__ xg,      // [b*PP][128]
    const float* __restrict__ ea2,    // [b][PP][8]
    const bf16* __restrict__ Wt,      // [256][128]  (Wev^T)
    const float* __restrict__ cbev,   // [256]
    const float* __restrict__ nin_ws, // [b*n][256]
    const bf16* __restrict__ WoB,     // [512][256]
    const float* __restrict__ cbo,    // [256]
    const bf16* __restrict__ WskB,    // [256][512]
    const float* __restrict__ cbsk,   // [512]
    const float* __restrict__ cnode,  // canonical fp32 node
    void* __restrict__ out, const int* __restrict__ flags)
{
  __shared__ __align__(16) bf16  xgS[128][128];   // 32 KB gathered neighbor rows
  __shared__ __align__(16) float sS[8][128];      // 4 KB per-head S vectors
  float* xc    = (float*)xgS;        // [512] aliases xgS after phase C
  float* combS = xc + 512;           // [256]
  const int t = threadIdx.x;
  const int bid = blockIdx.x;
  const int swz = (bid & 7)*128 + (bid >> 3);   // XCD j owns contiguous swz range = one b
  const int n = swz & 127, b = swz >> 7;
  const int g = b*NN + n;
  const int h = t >> 5, ln = t & 31;

  // ---- Issue phase: all global loads go out before any compute/barrier ----
  float4 qv[8];
  const float* qb = q_ws + (((long)b*NH + h)*NN + n)*DH;
  #pragma unroll
  for (int d4=0; d4<8; d4++) qv[d4] = *reinterpret_cast<const float4*>(qb + d4*4);
  float eav[4];
  const float* eab = ea2 + (long)b*PP*8;
  #pragma unroll
  for (int j=0;j<4;j++){
    int m = ln + 32*j;
    int ms = (m == n) ? (m ^ 1) : m;
    eav[j] = eab[(long)pair_idx(n, ms)*8 + h];
  }
  const bf16* xgb = xg + (long)b*PP*HE;
  const int rowb = t >> 4, seg = t & 15;
  float4 xr[8];
  #pragma unroll
  for (int it=0; it<8; ++it){
    int row = it*16 + rowb;
    int ms = (row == n) ? (row ^ 1) : row;
    int pr = pair_idx(n, ms);
    xr[it] = *reinterpret_cast<const float4*>(xgb + (long)pr*HE + seg*8);
  }

  // ---- Phase B: fp32 QK dots + per-head softmax, no LDS, no barrier ----
  const float scale = 0.17677669529663687f;  // 32^-0.5
  const float* kb = k_ws + ((long)b*NH + h)*NN*DH;
  float l[4];
  float mx = -INFINITY;
  int valid = 0;
  #pragma unroll
  for (int j=0;j<4;j++){
    int m = ln + 32*j;
    const float* kr = kb + m*DH;
    float dot = 0.f;
    #pragma unroll
    for (int d4=0; d4<8; d4++){
      float4 kv = *reinterpret_cast<const float4*>(kr + d4*4);
      dot = fmaf(qv[d4].x, kv.x, dot);
      dot = fmaf(qv[d4].y, kv.y, dot);
      dot = fmaf(qv[d4].z, kv.z, dot);
      dot = fmaf(qv[d4].w, kv.w, dot);
    }
    bool self = (m == n);
    l[j] = self ? -INFINITY : fmaf(dot, scale, eav[j]);
    if (!self && eav[j] > -8.9e15f) valid = 1;
    mx = fmaxf(mx, l[j]);
  }
  #pragma unroll
  for (int off=16; off>=1; off>>=1) mx = fmaxf(mx, __shfl_xor(mx, off, 32));
  float e[4], s = 0.f;
  #pragma unroll
  for (int j=0;j<4;j++){ e[j] = __expf(l[j]-mx); s += e[j]; }
  float av = valid ? 1.f : 0.f;
  #pragma unroll
  for (int off=16; off>=1; off>>=1){
    s  += __shfl_xor(s,  off, 32);
    av += __shfl_xor(av, off, 32);
  }
  float inv = (av > 0.f) ? (1.0f/s) : 0.f;
  float pj0 = e[0]*inv, pj1 = e[1]*inv, pj2 = e[2]*inv, pj3 = e[3]*inv;

  // ---- Stage gathered xg rows to LDS (loads landed during Phase B) ----
  #pragma unroll
  for (int it=0; it<8; ++it){
    int row = it*16 + rowb;
    *reinterpret_cast<float4*>(&xgS[row][seg*8]) = xr[it];
  }
  __syncthreads();

  // ---- Phase C: branch-free p-weighted accumulate (p via shuffle broadcast) ----
  const float* vb = v_ws + (long)b*NN*HN + h*DH + ln;
  float S0=0.f,S1=0.f,S2=0.f,S3=0.f,T=0.f;
  #pragma unroll
  for (int j=0;j<4;j++){
    float pcur = (j==0) ? pj0 : (j==1) ? pj1 : (j==2) ? pj2 : pj3;
    #pragma unroll 2
    for (int mm=0; mm<32; mm+=4){
      #pragma unroll
      for (int i=0;i<4;i++){
        int m = j*32 + mm + i;
        float pm = __shfl(pcur, mm + i, 32);
        short4 xv = *reinterpret_cast<const short4*>(&xgS[m][ln*4]);
        S0 = fmaf(pm, bfraw2f(xv.x), S0);
        S1 = fmaf(pm, bfraw2f(xv.y), S1);
        S2 = fmaf(pm, bfraw2f(xv.z), S2);
        S3 = fmaf(pm, bfraw2f(xv.w), S3);
        T  = fmaf(pm, vb[m*HN], T);
      }
    }
  }
  {
    float4 sv; sv.x=S0; sv.y=S1; sv.z=S2; sv.w=S3;
    *reinterpret_cast<float4*>(&sS[h][ln*4]) = sv;
  }
  __syncthreads();   // after this barrier xgS is dead -> xc/combS may be written

  // ---- Phase D: per-head 128x32 matvec with Wt, + bev + v-part = attn col t ----
  float nin_v = nin_ws[(long)g*HN + t];   // issue early; lands under matvec
  float acc = T + ((av > 0.f) ? cbev[t] : 0.f);
  const bf16* wr = Wt + t*HE;
  #pragma unroll 4
  for (int k0=0;k0<128;k0+=8){
    float4 sa = *reinterpret_cast<const float4*>(&sS[h][k0]);
    float4 sb = *reinterpret_cast<const float4*>(&sS[h][k0+4]);
    bf16x8 wv = *reinterpret_cast<const bf16x8*>(wr + k0);
    acc = fmaf(sa.x, bfraw2f(wv[0]), acc);
    acc = fmaf(sa.y, bfraw2f(wv[1]), acc);
    acc = fmaf(sa.z, bfraw2f(wv[2]), acc);
    acc = fmaf(sa.w, bfraw2f(wv[3]), acc);
    acc = fmaf(sb.x, bfraw2f(wv[4]), acc);
    acc = fmaf(sb.y, bfraw2f(wv[5]), acc);
    acc = fmaf(sb.z, bfraw2f(wv[6]), acc);
    acc = fmaf(sb.w, bfraw2f(wv[7]), acc);
  }
  xc[t]       = nin_v;
  xc[256 + t] = acc;
  __syncthreads();

  // ---- Phase E (k4): comb col t = GELU(bo + concat(nin,attn) . Wo[:,t]) ----
  // WoB[k][t]: lane-contiguous (coalesced 512B/instr); xc[k] is LDS broadcast.
  float co = cbo[t];
  #pragma unroll 8
  for (int k=0;k<512;k++){
    co = fmaf(xc[k], bf2f(WoB[k*HN + t]), co);
  }
  co = 0.5f*co*(1.0f + erff(co*0.7071067811865475f));
  combS[t] = co;
  __syncthreads();

  // ---- Phase F (k5): val/gate cols t / t+256 of Wsk, sigmoid gate + residual ----
  float av5 = cbsk[t], ag5 = cbsk[t+256];
  #pragma unroll 8
  for (int k=0;k<256;k++){
    float cx = combS[k];
    av5 = fmaf(cx, bf2f(WskB[k*512 + t]), av5);
    ag5 = fmaf(cx, bf2f(WskB[k*512 + t + 256]), ag5);
  }
  float gg = 1.0f/(1.0f + __expf(-ag5));
  long idx = (long)g*HN + t;
  float nf = cnode[idx];
  float res = nf*(1.0f - gg) + av5*gg;
  if (flags[0]) ((float*)out)[idx] = res;
  else ((bf16*)out)[idx] = __float2bfloat16(res);
}

extern "C" void kernel_launch(void* const* d_in, const int* in_sizes, int n_inputs,
                              void* d_out, int out_size, void* d_ws, size_t ws_size,
                              hipStream_t stream)
{
  float* ws = (float*)d_ws;
  float* c_node = ws + C_NODE;
  float* c_mask = ws + C_MASK;
  float* c_Wqkv = ws + C_WQKV;
  float* c_bqkv = ws + C_BQKV;
  float* c_bev  = ws + C_BEV;
  float* c_Wea  = ws + C_WEA;
  float* c_bea  = ws + C_BEA;
  float* c_bo   = ws + C_BO;
  float* c_bsk  = ws + C_BSK;
  float* c_gn   = ws + C_GN;
  float* c_bn   = ws + C_BN;
  float* c_ge   = ws + C_GE;
  float* c_be   = ws + C_BE;
  float* base   = ws + IOFF;
  float* nin_ws  = base + I_NIN;
  float* q_ws    = base + I_Q;
  float* k_ws    = base + I_K;
  float* v_ws    = base + I_V;
  float* ea2_ws  = base + I_EA2;
  bf16*  xg_ws   = (bf16*)(base + I_XG);
  bf16*  wt_ws   = (bf16*)(base + I_WT);
  bf16*  wob_ws  = (bf16*)(base + I_WOB);
  bf16*  wskb_ws = (bf16*)(base + I_WSKB);
  int*   flags   = (int*)(base + I_FLG);

  SrcPtrs sp;
  sp.p[0]  = d_in[0];   // node_feat
  sp.p[1]  = d_in[4];   // mask_valid
  sp.p[2]  = d_in[5];   // Wqkv
  sp.p[3]  = d_in[6];   // bqkv
  sp.p[4]  = d_in[7];   // Wev
  sp.p[5]  = d_in[8];   // bev
  sp.p[6]  = d_in[9];   // Wea
  sp.p[7]  = d_in[10];  // bea
  sp.p[8]  = d_in[11];  // Wo
  sp.p[9]  = d_in[12];  // bo
  sp.p[10] = d_in[13];  // Wsk
  sp.p[11] = d_in[14];  // bsk
  sp.p[12] = d_in[15];  // gn
  sp.p[13] = d_in[16];  // bn
  sp.p[14] = d_in[17];  // ge
  sp.p[15] = d_in[18];  // be

  k_convert<<<CONVBLKS + 256, 256, 0, stream>>>(sp, ws, flags,
                                                (const unsigned short*)d_in[0],
                                                d_in[7], wt_ws,
                                                d_in[11], d_in[13],
                                                wob_ws, wskb_ws);
  k1_node_ln_qkv<<<768, 256, 0, stream>>>(c_node, c_Wqkv, c_bqkv, c_gn, c_bn,
                                          nin_ws, q_ws, k_ws, v_ws);
  k2a_edge_ln<<<BP/16, 256, 0, stream>>>(d_in[1], c_Wea, c_bea, c_ge, c_be, c_mask,
                                         xg_ws, ea2_ws, flags);
  k345<<<BB*NN, 256, 0, stream>>>(q_ws, k_ws, v_ws, xg_ws, ea2_ws, wt_ws, c_bev,
                                  nin_ws, wob_ws, c_bo, wskb_ws, c_bsk,
                                  c_node, d_out, flags);
}

// Round 12
// 190.405 us; speedup vs baseline: 1.3453x; 1.0895x over previous
//
#include <hip/hip_runtime.h>
#include <hip/hip_bf16.h>
#include <math.h>

#define BB 8
#define NN 128
#define HN 256
#define HE 128
#define NH 8
#define DH 32
#define PP 8128
#define BP (BB*PP)   // 65024

typedef __hip_bfloat16 bf16;
typedef __attribute__((ext_vector_type(8))) short bf16x8;

__device__ __forceinline__ float bf2f(bf16 x){ return __bfloat162float(x); }
__device__ __forceinline__ float bfraw2f(short u){
  return __uint_as_float(((unsigned)(unsigned short)u) << 16);
}

__device__ __forceinline__ float wave_sum(float v){
  #pragma unroll
  for (int off=32; off>=1; off>>=1) v += __shfl_xor(v, off, 64);
  return v;
}
__device__ __forceinline__ float g16_sum(float v){
  #pragma unroll
  for (int off=8; off>=1; off>>=1) v += __shfl_xor(v, off, 16);
  return v;
}

// triu pair index for N=128, i<j: p = i*(255-i)/2 + (j-i-1)
__device__ __forceinline__ int pair_idx(int a, int c){
  int i = a < c ? a : c;
  int j = a < c ? c : a;
  return ((i*(255 - i))>>1) + (j - i - 1);
}

// ---- canonical fp32 workspace layout (float offsets). edge_feat NOT converted. ----
#define C_NODE 0LL
#define C_MASK 262144LL
#define C_WQKV 327168LL
#define C_BQKV 523776LL
#define C_WEV  524544LL
#define C_BEV  557312LL
#define C_WEA  557568LL
#define C_BEA  558592LL
#define C_WO   558600LL
#define C_BO   689672LL
#define C_WSK  689928LL
#define C_BSK  821000LL
#define C_GN   821512LL
#define C_BN   821768LL
#define C_GE   822024LL
#define C_BE   822152LL
#define IOFF   822400LL
#define TOT8   102785
#define CONVBLKS 402          // ceil(TOT8/256)
// intermediates (float offsets from IOFF)
#define I_NIN  0LL
#define I_Q    262144LL
#define I_K    524288LL
#define I_V    786432LL
#define I_EA2  1572864LL   // [B][PP][8] f32 = 520192
#define I_XG   2093056LL   // [BP][128] bf16 = 4161536 float-slots
#define I_WT   14577664LL  // [256][128] bf16 = 16384 float-slots
#define I_WOB  14594048LL  // WoB [512][256] bf16 = 65536 float-slots
#define I_WSKB 14659584LL  // WskB [256][512] bf16 = 65536 float-slots
#define I_FLG  14725120LL

// ---------------- Converter + Wev^T + WoB/WskB bf16 (same layout) + dtype detect --
struct SrcPtrs { const void* p[16]; };

__global__ __launch_bounds__(256) void k_convert(SrcPtrs sp, float* __restrict__ dst,
                                                 int* __restrict__ flags,
                                                 const unsigned short* __restrict__ nodeRaw,
                                                 const void* __restrict__ rawWev,
                                                 bf16* __restrict__ Wt,
                                                 const void* __restrict__ rawWo,
                                                 const void* __restrict__ rawWsk,
                                                 bf16* __restrict__ WoB,
                                                 bf16* __restrict__ WskB)
{
  __shared__ int sbad;
  if (threadIdx.x == 0) sbad = 0;
  __syncthreads();
  {
    int bad = 0;
    for (int i = threadIdx.x; i < 1024; i += 256){
      unsigned e = (nodeRaw[i] >> 7) & 0xFFu;
      if (e >= 194u) bad = 1;
    }
    if (bad) sbad = 1;
  }
  __syncthreads();
  const int f32 = sbad;        // 1 = inputs fp32, 0 = bf16
  if (blockIdx.x == 0 && threadIdx.x == 0) flags[0] = f32;

  if (blockIdx.x >= CONVBLKS + 128){
    // Wo / Wsk -> bf16, same [k][n] layout. 32768 octets total.
    int o = (blockIdx.x - (CONVBLKS + 128))*256 + threadIdx.x;   // < 32768
    const void* src = (o < 16384) ? rawWo : rawWsk;
    bf16* dw = (o < 16384) ? WoB : WskB;
    int lo = (o < 16384) ? o : o - 16384;
    if (f32){
      const float4* s4 = (const float4*)src;
      float4 a0 = s4[2*lo], a1 = s4[2*lo+1];
      union { float4 f; bf16 h[8]; } cv;
      cv.h[0]=__float2bfloat16(a0.x); cv.h[1]=__float2bfloat16(a0.y);
      cv.h[2]=__float2bfloat16(a0.z); cv.h[3]=__float2bfloat16(a0.w);
      cv.h[4]=__float2bfloat16(a1.x); cv.h[5]=__float2bfloat16(a1.y);
      cv.h[6]=__float2bfloat16(a1.z); cv.h[7]=__float2bfloat16(a1.w);
      *reinterpret_cast<float4*>(dw + lo*8) = cv.f;
    } else {
      *reinterpret_cast<float4*>(dw + lo*8) = ((const float4*)src)[lo];  // bit-exact copy
    }
    return;
  }

  if (blockIdx.x >= CONVBLKS){
    // Wev transpose from RAW input: idx over [128][256] -> Wt [256][128] bf16
    int idx = (blockIdx.x - CONVBLKS)*256 + threadIdx.x;   // < 32768
    float v = f32 ? ((const float*)rawWev)[idx]
                  : bfraw2f(((const short*)rawWev)[idx]);
    Wt[(idx & 255)*128 + (idx >> 8)] = __float2bfloat16(v);
    return;
  }

  int o = blockIdx.x*256 + threadIdx.x;
  if (o >= TOT8) return;
  const int cum[17] = {0,32768,40896,65472,65568,69664,69696,69824,69825,
                       86209,86241,102625,102689,102721,102753,102769,102785};
  int s = 0;
  #pragma unroll
  for (int i = 1; i <= 15; i++) if (o >= cum[i]) s = i;
  const int li = o - cum[s];
  float4 r0, r1;
  if (f32){
    const float4* src = (const float4*)sp.p[s];
    r0 = src[2*li]; r1 = src[2*li+1];
  } else {
    union { float4 f; unsigned short u[8]; } cv;
    cv.f = ((const float4*)sp.p[s])[li];
    r0.x = __uint_as_float((unsigned)cv.u[0] << 16);
    r0.y = __uint_as_float((unsigned)cv.u[1] << 16);
    r0.z = __uint_as_float((unsigned)cv.u[2] << 16);
    r0.w = __uint_as_float((unsigned)cv.u[3] << 16);
    r1.x = __uint_as_float((unsigned)cv.u[4] << 16);
    r1.y = __uint_as_float((unsigned)cv.u[5] << 16);
    r1.z = __uint_as_float((unsigned)cv.u[6] << 16);
    r1.w = __uint_as_float((unsigned)cv.u[7] << 16);
  }
  float4* d = (float4*)(dst + (long long)cum[s]*8);
  d[2*li]   = r0;
  d[2*li+1] = r1;
}

// ---------------- Kernel 1: node LN + QKV GEMM, column-split x3 ----------------
// grid 768 = 256 rowgroups(4 rows) x 3 outputs {q,k,v}; block 256
// v is stored row-major [b][n][256] (col = h*32+d) for the fused attention kernel.
__global__ __launch_bounds__(256) void k1_node_ln_qkv(
    const float* __restrict__ cnode, const float* __restrict__ cWqkv,
    const float* __restrict__ cbqkv, const float* __restrict__ cgn, const float* __restrict__ cbn,
    float* __restrict__ nin_ws, float* __restrict__ q_ws, float* __restrict__ k_ws,
    float* __restrict__ v_ws)
{
  __shared__ float xln[4][HN];
  const int t = threadIdx.x, wv = t>>6, lane = t&63;
  const int cb = blockIdx.x % 3;           // 0=q, 1=k, 2=v
  const int g0 = (blockIdx.x / 3) * 4;
  {
    int g = g0 + wv;
    float x[4];
    #pragma unroll
    for (int i=0;i<4;i++) x[i] = cnode[g*HN + lane + 64*i];
    float s = x[0]+x[1]+x[2]+x[3];
    s = wave_sum(s);
    float m = s * (1.0f/HN);
    float q = 0.f;
    #pragma unroll
    for (int i=0;i<4;i++){ float d = x[i]-m; q += d*d; }
    q = wave_sum(q);
    float rstd = rsqrtf(fmaxf(q*(1.0f/HN), 0.f) + 1e-5f);
    #pragma unroll
    for (int i=0;i<4;i++){
      int c = lane + 64*i;
      float y = (x[i]-m)*rstd*cgn[c] + cbn[c];
      xln[wv][c] = y;
      if (cb == 0) nin_ws[g*HN + c] = y;
    }
  }
  __syncthreads();
  const int col = cb*256 + t;
  float acc[4];
  {
    float bb = cbqkv[col];
    #pragma unroll
    for (int r=0;r<4;r++) acc[r] = bb;
  }
  for (int k=0;k<HN;k+=4){
    float4 xv[4];
    #pragma unroll
    for (int r=0;r<4;r++) xv[r] = *reinterpret_cast<const float4*>(&xln[r][k]);
    #pragma unroll
    for (int kk=0;kk<4;kk++){
      float w = cWqkv[(k+kk)*768 + col];
      #pragma unroll
      for (int r=0;r<4;r++) acc[r] = fmaf((&xv[r].x)[kk], w, acc[r]);
    }
  }
  if (cb == 2){
    // v: row-major [b][n][256], col = t = h*32+d
    #pragma unroll
    for (int r=0;r<4;r++) v_ws[(long)(g0+r)*HN + t] = acc[r];
  } else {
    float* dstp = (cb == 0) ? q_ws : k_ws;
    const int h = t>>5, d = t&31;
    #pragma unroll
    for (int r=0;r<4;r++){
      int g = g0 + r;
      int b = g>>7, n = g&127;
      dstp[((b*NH + h)*NN + n)*DH + d] = acc[r];
    }
  }
}

// ---------------- k2a: edge LN -> xg (bf16), Wea GEMM + mask fold -> ea2 ----------
// grid 4064 (16 rows/block), block 256
// ea2 layout is [b][p][8] so the attention kernel gathers 32 contiguous bytes/pair.
__global__ __launch_bounds__(256) void k2a_edge_ln(
    const void* __restrict__ edge_raw, const float* __restrict__ cWea,
    const float* __restrict__ cbea, const float* __restrict__ cge,
    const float* __restrict__ cbe, const float* __restrict__ cmask,
    bf16* __restrict__ xg, float* __restrict__ ea2, const int* __restrict__ flags)
{
  __shared__ float xlnS[16][136];
  __shared__ float part[128];
  const int t = threadIdx.x;
  const int R0 = blockIdx.x*16;
  const int b = R0 / PP;
  const int p0 = R0 - b*PP;
  const int f32 = flags[0];
  {
    int r = t>>4, sub = t&15;
    long base = (long)(R0 + r)*HE + sub*8;
    float x[8];
    if (f32){
      const float* cef = (const float*)edge_raw + base;
      float4 a0 = *reinterpret_cast<const float4*>(cef);
      float4 a1 = *reinterpret_cast<const float4*>(cef + 4);
      x[0]=a0.x; x[1]=a0.y; x[2]=a0.z; x[3]=a0.w;
      x[4]=a1.x; x[5]=a1.y; x[6]=a1.z; x[7]=a1.w;
    } else {
      union { float4 f; short u[8]; } cv;
      cv.f = *reinterpret_cast<const float4*>((const bf16*)edge_raw + base);
      #pragma unroll
      for (int i=0;i<8;i++) x[i] = bfraw2f(cv.u[i]);
    }
    float s = 0.f;
    #pragma unroll
    for (int i=0;i<8;i++) s += x[i];
    s = g16_sum(s);
    float m = s*(1.0f/HE);
    float q = 0.f;
    #pragma unroll
    for (int i=0;i<8;i++){ float dd = x[i]-m; q += dd*dd; }
    q = g16_sum(q);
    float rstd = rsqrtf(fmaxf(q*(1.0f/HE), 0.f) + 1e-5f);
    float y[8];
    #pragma unroll
    for (int i=0;i<8;i++){
      int c = sub*8 + i;
      y[i] = (x[i]-m)*rstd*cge[c] + cbe[c];
    }
    float4 y0; y0.x=y[0]; y0.y=y[1]; y0.z=y[2]; y0.w=y[3];
    float4 y1; y1.x=y[4]; y1.y=y[5]; y1.z=y[6]; y1.w=y[7];
    *reinterpret_cast<float4*>(&xlnS[r][sub*8])     = y0;
    *reinterpret_cast<float4*>(&xlnS[r][sub*8 + 4]) = y1;
  }
  __syncthreads();
  // write xg: thread -> row = t>>4, 8 consecutive cols
  {
    int r = t>>4, c0 = (t&15)*8;
    union { float4 f; bf16 h[8]; } o;
    #pragma unroll
    for (int i=0;i<8;i++) o.h[i] = __float2bfloat16(xlnS[r][c0+i]);
    *reinterpret_cast<float4*>(xg + (long)(R0 + r)*HE + c0) = o.f;
  }
  // e_adj (+mask fold): all 256 threads; (r,c) with k-range split by half
  {
    const int c = t & 7, r = (t>>3) & 15, half = t>>7;
    const int pid = r*8 + c;
    float s = half ? 0.0f : cbea[c];
    const int k0 = half*64;
    #pragma unroll 8
    for (int k=k0; k<k0+64; k++) s = fmaf(xlnS[r][k], cWea[k*NH + c], s);
    if (half){ part[pid] = s; }
    __syncthreads();
    if (!half){
      s += part[pid];
      int p = p0 + r;
      float mk = cmask[b*PP + p];
      ea2[((long)b*PP + p)*8 + c] = (mk != 0.0f) ? s : -9e15f;
    }
  }
}

// ------- k345: fused attention + Wo/GELU + Wsk/gate/residual, per (b,n) row ------
// Tail phases E/F use 8-cols/thread + K-split-8 with bf16x8 weight loads:
// 8 FMA per 16B coalesced load (round-9's scalar tail was 1 FMA per 2B load,
// issue/latency-bound at 38us). Partial sums reduced through LDS.
// grid B*N = 1024 (XCD-swizzled); block 256 (32 lanes/head); LDS 36.9KB -> 4 blk/CU
__global__ __launch_bounds__(256, 4) void k345(
    const float* __restrict__ q_ws,   // [b][h][n][32]
    const float* __restrict__ k_ws,   // [b][h][n][32]
    const float* __restrict__ v_ws,   // [b][n][256]
    const bf16* __restrict__ xg,      // [b*PP][128]
    const float* __restrict__ ea2,    // [b][PP][8]
    const bf16* __restrict__ Wt,      // [256][128]  (Wev^T)
    const float* __restrict__ cbev,   // [256]
    const float* __restrict__ nin_ws, // [b*n][256]
    const bf16* __restrict__ WoB,     // [512][256]
    const float* __restrict__ cbo,    // [256]
    const bf16* __restrict__ WskB,    // [256][512]
    const float* __restrict__ cbsk,   // [512]
    const float* __restrict__ cnode,  // canonical fp32 node
    void* __restrict__ out, const int* __restrict__ flags)
{
  __shared__ __align__(16) bf16  xgS[128][128];   // 32 KB gathered neighbor rows
  __shared__ __align__(16) float sS[8][128];      // 4 KB per-head S vectors
  float* xc    = (float*)xgS;        // [512] aliases xgS after phase C
  float* combS = xc + 512;           // [256]
  float* psE   = xc + 768;           // [8][256] phase-E partials (reused by F)
  float* psG   = xc + 768 + 2048;    // [8][256] phase-F gate partials
  const int t = threadIdx.x;
  const int bid = blockIdx.x;
  const int swz = (bid & 7)*128 + (bid >> 3);   // XCD j owns contiguous swz range = one b
  const int n = swz & 127, b = swz >> 7;
  const int g = b*NN + n;
  const int h = t >> 5, ln = t & 31;

  // ---- Issue phase: all global loads go out before any compute/barrier ----
  float4 qv[8];
  const float* qb = q_ws + (((long)b*NH + h)*NN + n)*DH;
  #pragma unroll
  for (int d4=0; d4<8; d4++) qv[d4] = *reinterpret_cast<const float4*>(qb + d4*4);
  float eav[4];
  const float* eab = ea2 + (long)b*PP*8;
  #pragma unroll
  for (int j=0;j<4;j++){
    int m = ln + 32*j;
    int ms = (m == n) ? (m ^ 1) : m;
    eav[j] = eab[(long)pair_idx(n, ms)*8 + h];
  }
  const bf16* xgb = xg + (long)b*PP*HE;
  const int rowb = t >> 4, seg = t & 15;
  float4 xr[8];
  #pragma unroll
  for (int it=0; it<8; ++it){
    int row = it*16 + rowb;
    int ms = (row == n) ? (row ^ 1) : row;
    int pr = pair_idx(n, ms);
    xr[it] = *reinterpret_cast<const float4*>(xgb + (long)pr*HE + seg*8);
  }

  // ---- Phase B: fp32 QK dots + per-head softmax, no LDS, no barrier ----
  const float scale = 0.17677669529663687f;  // 32^-0.5
  const float* kb = k_ws + ((long)b*NH + h)*NN*DH;
  float l[4];
  float mx = -INFINITY;
  int valid = 0;
  #pragma unroll
  for (int j=0;j<4;j++){
    int m = ln + 32*j;
    const float* kr = kb + m*DH;
    float dot = 0.f;
    #pragma unroll
    for (int d4=0; d4<8; d4++){
      float4 kv = *reinterpret_cast<const float4*>(kr + d4*4);
      dot = fmaf(qv[d4].x, kv.x, dot);
      dot = fmaf(qv[d4].y, kv.y, dot);
      dot = fmaf(qv[d4].z, kv.z, dot);
      dot = fmaf(qv[d4].w, kv.w, dot);
    }
    bool self = (m == n);
    l[j] = self ? -INFINITY : fmaf(dot, scale, eav[j]);
    if (!self && eav[j] > -8.9e15f) valid = 1;
    mx = fmaxf(mx, l[j]);
  }
  #pragma unroll
  for (int off=16; off>=1; off>>=1) mx = fmaxf(mx, __shfl_xor(mx, off, 32));
  float e[4], s = 0.f;
  #pragma unroll
  for (int j=0;j<4;j++){ e[j] = __expf(l[j]-mx); s += e[j]; }
  float av = valid ? 1.f : 0.f;
  #pragma unroll
  for (int off=16; off>=1; off>>=1){
    s  += __shfl_xor(s,  off, 32);
    av += __shfl_xor(av, off, 32);
  }
  float inv = (av > 0.f) ? (1.0f/s) : 0.f;
  float pj0 = e[0]*inv, pj1 = e[1]*inv, pj2 = e[2]*inv, pj3 = e[3]*inv;

  // ---- Stage gathered xg rows to LDS (loads landed during Phase B) ----
  #pragma unroll
  for (int it=0; it<8; ++it){
    int row = it*16 + rowb;
    *reinterpret_cast<float4*>(&xgS[row][seg*8]) = xr[it];
  }
  __syncthreads();

  // ---- Phase C: branch-free p-weighted accumulate (p via shuffle broadcast) ----
  const float* vb = v_ws + (long)b*NN*HN + h*DH + ln;
  float S0=0.f,S1=0.f,S2=0.f,S3=0.f,T=0.f;
  #pragma unroll
  for (int j=0;j<4;j++){
    float pcur = (j==0) ? pj0 : (j==1) ? pj1 : (j==2) ? pj2 : pj3;
    #pragma unroll 2
    for (int mm=0; mm<32; mm+=4){
      #pragma unroll
      for (int i=0;i<4;i++){
        int m = j*32 + mm + i;
        float pm = __shfl(pcur, mm + i, 32);
        short4 xv = *reinterpret_cast<const short4*>(&xgS[m][ln*4]);
        S0 = fmaf(pm, bfraw2f(xv.x), S0);
        S1 = fmaf(pm, bfraw2f(xv.y), S1);
        S2 = fmaf(pm, bfraw2f(xv.z), S2);
        S3 = fmaf(pm, bfraw2f(xv.w), S3);
        T  = fmaf(pm, vb[m*HN], T);
      }
    }
  }
  {
    float4 sv; sv.x=S0; sv.y=S1; sv.z=S2; sv.w=S3;
    *reinterpret_cast<float4*>(&sS[h][ln*4]) = sv;
  }
  __syncthreads();   // after this barrier xgS is dead -> xc/combS/ps may be written

  // ---- Phase D: per-head 128x32 matvec with Wt, + bev + v-part = attn col t ----
  float nin_v = nin_ws[(long)g*HN + t];   // issue early; lands under matvec
  float acc = T + ((av > 0.f) ? cbev[t] : 0.f);
  const bf16* wr = Wt + t*HE;
  #pragma unroll 4
  for (int k0=0;k0<128;k0+=8){
    float4 sa = *reinterpret_cast<const float4*>(&sS[h][k0]);
    float4 sb = *reinterpret_cast<const float4*>(&sS[h][k0+4]);
    bf16x8 wv = *reinterpret_cast<const bf16x8*>(wr + k0);
    acc = fmaf(sa.x, bfraw2f(wv[0]), acc);
    acc = fmaf(sa.y, bfraw2f(wv[1]), acc);
    acc = fmaf(sa.z, bfraw2f(wv[2]), acc);
    acc = fmaf(sa.w, bfraw2f(wv[3]), acc);
    acc = fmaf(sb.x, bfraw2f(wv[4]), acc);
    acc = fmaf(sb.y, bfraw2f(wv[5]), acc);
    acc = fmaf(sb.z, bfraw2f(wv[6]), acc);
    acc = fmaf(sb.w, bfraw2f(wv[7]), acc);
  }
  xc[t]       = nin_v;
  xc[256 + t] = acc;
  __syncthreads();

  // ---- Phase E (k4): 8 cols/thread, K-split 8, bf16x8 weight loads ----
  {
    const int c8 = t & 31, ks = t >> 5;       // ks uniform per half-wave
    const int cbase = c8*8;
    float a8[8];
    #pragma unroll
    for (int i=0;i<8;i++) a8[i] = 0.f;
    const bf16* wp = WoB + (long)(ks*64)*HN + cbase;
    #pragma unroll 8
    for (int kk=0; kk<64; ++kk){
      float xk = xc[ks*64 + kk];              // LDS broadcast (2 addrs/wave)
      bf16x8 w8 = *reinterpret_cast<const bf16x8*>(wp);
      wp += HN;
      a8[0] = fmaf(xk, bfraw2f(w8[0]), a8[0]);
      a8[1] = fmaf(xk, bfraw2f(w8[1]), a8[1]);
      a8[2] = fmaf(xk, bfraw2f(w8[2]), a8[2]);
      a8[3] = fmaf(xk, bfraw2f(w8[3]), a8[3]);
      a8[4] = fmaf(xk, bfraw2f(w8[4]), a8[4]);
      a8[5] = fmaf(xk, bfraw2f(w8[5]), a8[5]);
      a8[6] = fmaf(xk, bfraw2f(w8[6]), a8[6]);
      a8[7] = fmaf(xk, bfraw2f(w8[7]), a8[7]);
    }
    #pragma unroll
    for (int i=0;i<8;i++) psE[ks*256 + c8 + 32*i] = a8[i];   // bank-free
  }
  __syncthreads();
  {
    int idx = (t>>3) + 32*(t&7);              // col t -> (c8=t>>3, i=t&7)
    float co = cbo[t];
    #pragma unroll
    for (int ks=0; ks<8; ++ks) co += psE[ks*256 + idx];
    co = 0.5f*co*(1.0f + erff(co*0.7071067811865475f));
    combS[t] = co;
  }
  __syncthreads();

  // ---- Phase F (k5): val/gate 8 cols/thread, K-split 8, bf16x8 loads ----
  {
    const int c8 = t & 31, ks = t >> 5;
    const int cbase = c8*8;
    float av8[8], ag8[8];
    #pragma unroll
    for (int i=0;i<8;i++){ av8[i] = 0.f; ag8[i] = 0.f; }
    const bf16* wvp = WskB + (long)(ks*32)*512 + cbase;
    const bf16* wgp = wvp + 256;
    #pragma unroll 4
    for (int kk=0; kk<32; ++kk){
      float cx = combS[ks*32 + kk];
      bf16x8 wv8 = *reinterpret_cast<const bf16x8*>(wvp);
      bf16x8 wg8 = *reinterpret_cast<const bf16x8*>(wgp);
      wvp += 512; wgp += 512;
      av8[0] = fmaf(cx, bfraw2f(wv8[0]), av8[0]);
      av8[1] = fmaf(cx, bfraw2f(wv8[1]), av8[1]);
      av8[2] = fmaf(cx, bfraw2f(wv8[2]), av8[2]);
      av8[3] = fmaf(cx, bfraw2f(wv8[3]), av8[3]);
      av8[4] = fmaf(cx, bfraw2f(wv8[4]), av8[4]);
      av8[5] = fmaf(cx, bfraw2f(wv8[5]), av8[5]);
      av8[6] = fmaf(cx, bfraw2f(wv8[6]), av8[6]);
      av8[7] = fmaf(cx, bfraw2f(wv8[7]), av8[7]);
      ag8[0] = fmaf(cx, bfraw2f(wg8[0]), ag8[0]);
      ag8[1] = fmaf(cx, bfraw2f(wg8[1]), ag8[1]);
      ag8[2] = fmaf(cx, bfraw2f(wg8[2]), ag8[2]);
      ag8[3] = fmaf(cx, bfraw2f(wg8[3]), ag8[3]);
      ag8[4] = fmaf(cx, bfraw2f(wg8[4]), ag8[4]);
      ag8[5] = fmaf(cx, bfraw2f(wg8[5]), ag8[5]);
      ag8[6] = fmaf(cx, bfraw2f(wg8[6]), ag8[6]);
      ag8[7] = fmaf(cx, bfraw2f(wg8[7]), ag8[7]);
    }
    #pragma unroll
    for (int i=0;i<8;i++){
      psE[ks*256 + c8 + 32*i] = av8[i];       // psE reused for val partials
      psG[ks*256 + c8 + 32*i] = ag8[i];
    }
  }
  __syncthreads();
  {
    int idx = (t>>3) + 32*(t&7);
    float av5 = cbsk[t], ag5 = cbsk[t+256];
    #pragma unroll
    for (int ks=0; ks<8; ++ks){
      av5 += psE[ks*256 + idx];
      ag5 += psG[ks*256 + idx];
    }
    float gg = 1.0f/(1.0f + __expf(-ag5));
    long idxg = (long)g*HN + t;
    float nf = cnode[idxg];
    float res = nf*(1.0f - gg) + av5*gg;
    if (flags[0]) ((float*)out)[idxg] = res;
    else ((bf16*)out)[idxg] = __float2bfloat16(res);
  }
}

extern "C" void kernel_launch(void* const* d_in, const int* in_sizes, int n_inputs,
                              void* d_out, int out_size, void* d_ws, size_t ws_size,
                              hipStream_t stream)
{
  float* ws = (float*)d_ws;
  float* c_node = ws + C_NODE;
  float* c_mask = ws + C_MASK;
  float* c_Wqkv = ws + C_WQKV;
  float* c_bqkv = ws + C_BQKV;
  float* c_bev  = ws + C_BEV;
  float* c_Wea  = ws + C_WEA;
  float* c_bea  = ws + C_BEA;
  float* c_bo   = ws + C_BO;
  float* c_bsk  = ws + C_BSK;
  float* c_gn   = ws + C_GN;
  float* c_bn   = ws + C_BN;
  float* c_ge   = ws + C_GE;
  float* c_be   = ws + C_BE;
  float* base   = ws + IOFF;
  float* nin_ws  = base + I_NIN;
  float* q_ws    = base + I_Q;
  float* k_ws    = base + I_K;
  float* v_ws    = base + I_V;
  float* ea2_ws  = base + I_EA2;
  bf16*  xg_ws   = (bf16*)(base + I_XG);
  bf16*  wt_ws   = (bf16*)(base + I_WT);
  bf16*  wob_ws  = (bf16*)(base + I_WOB);
  bf16*  wskb_ws = (bf16*)(base + I_WSKB);
  int*   flags   = (int*)(base + I_FLG);

  SrcPtrs sp;
  sp.p[0]  = d_in[0];   // node_feat
  sp.p[1]  = d_in[4];   // mask_valid
  sp.p[2]  = d_in[5];   // Wqkv
  sp.p[3]  = d_in[6];   // bqkv
  sp.p[4]  = d_in[7];   // Wev
  sp.p[5]  = d_in[8];   // bev
  sp.p[6]  = d_in[9];   // Wea
  sp.p[7]  = d_in[10];  // bea
  sp.p[8]  = d_in[11];  // Wo
  sp.p[9]  = d_in[12];  // bo
  sp.p[10] = d_in[13];  // Wsk
  sp.p[11] = d_in[14];  // bsk
  sp.p[12] = d_in[15];  // gn
  sp.p[13] = d_in[16];  // bn
  sp.p[14] = d_in[17];  // ge
  sp.p[15] = d_in[18];  // be

  k_convert<<<CONVBLKS + 256, 256, 0, stream>>>(sp, ws, flags,
                                                (const unsigned short*)d_in[0],
                                                d_in[7], wt_ws,
                                                d_in[11], d_in[13],
                                                wob_ws, wskb_ws);
  k1_node_ln_qkv<<<768, 256, 0, stream>>>(c_node, c_Wqkv, c_bqkv, c_gn, c_bn,
                                          nin_ws, q_ws, k_ws, v_ws);
  k2a_edge_ln<<<BP/16, 256, 0, stream>>>(d_in[1], c_Wea, c_bea, c_ge, c_be, c_mask,
                                         xg_ws, ea2_ws, flags);
  k345<<<BB*NN, 256, 0, stream>>>(q_ws, k_ws, v_ws, xg_ws, ea2_ws, wt_ws, c_bev,
                                  nin_ws, wob_ws, c_bo, wskb_ws, c_bsk,
                                  c_node, d_out, flags);
}